// Round 1
// baseline (316.821 us; speedup 1.0000x reference)
//
#include <hip/hip_runtime.h>

// Spatial Transformer: B=256, C=32, H=W=64. All fp32.
// Pipeline:
//   k1: partial layer-1 GEMM  s1_partial[kg][b][j]           (stored in d_out head)
//   k2: reduce + bias/relu + layer2 + layer3 -> theta[256,8]  (stored in d_out tail)
//   k3: affine grid + bilinear sample for all but last 2048 elements
//   k3tail: last 2048 elements (which overlap theta storage; read-then-write)

#define K_TOT 131072   // C*H*W
#define KG    128      // k-groups for layer-1 partials
#define KCH   (K_TOT / KG)  // 1024

__global__ __launch_bounds__(256) void st_lin1(const float* __restrict__ x,
                                               const float* __restrict__ w1,
                                               float* __restrict__ partial) {
    const int kg   = blockIdx.x;                                   // 0..KG
    const int g    = blockIdx.y;                                   // 0..4 (batch group)
    const int lane = threadIdx.x & 63;
    const int wave = __builtin_amdgcn_readfirstlane(threadIdx.x >> 6); // 0..3, uniform
    const int b    = g * 64 + lane;

    const float* xr = x  + (size_t)b * K_TOT + (size_t)kg * KCH;
    const float* wr = w1 + (size_t)(wave * 8) * K_TOT + (size_t)kg * KCH; // uniform

    float acc[8] = {0.f, 0.f, 0.f, 0.f, 0.f, 0.f, 0.f, 0.f};

    for (int k = 0; k < KCH; k += 8) {
        const float4 xa = *(const float4*)(xr + k);
        const float4 xb = *(const float4*)(xr + k + 4);
#pragma unroll
        for (int jj = 0; jj < 8; ++jj) {
            const float* wp = wr + (size_t)jj * K_TOT + k;   // wave-uniform -> s_load
            const float4 wa = *(const float4*)(wp);
            const float4 wb = *(const float4*)(wp + 4);
            acc[jj] += xa.x * wa.x + xa.y * wa.y + xa.z * wa.z + xa.w * wa.w
                     + xb.x * wb.x + xb.y * wb.y + xb.z * wb.z + xb.w * wb.w;
        }
    }

    float* pout = partial + ((size_t)kg * 256 + b) * 32 + wave * 8;
    *(float4*)(pout)     = make_float4(acc[0], acc[1], acc[2], acc[3]);
    *(float4*)(pout + 4) = make_float4(acc[4], acc[5], acc[6], acc[7]);
}

__global__ __launch_bounds__(64) void st_mlp(const float* __restrict__ partial,
                                             const float* __restrict__ b1,
                                             const float* __restrict__ w2,
                                             const float* __restrict__ b2,
                                             const float* __restrict__ w3,
                                             const float* __restrict__ b3,
                                             float* __restrict__ theta) {
    const int b = blockIdx.x;
    const int j = threadIdx.x;
    __shared__ float s1s[32];
    __shared__ float s2s[32];

    if (j < 32) {
        float s = b1[j];
        for (int kg = 0; kg < KG; ++kg)
            s += partial[((size_t)kg * 256 + b) * 32 + j];
        s1s[j] = fmaxf(s, 0.f);
    }
    __syncthreads();
    if (j < 32) {
        float s = b2[j];
#pragma unroll
        for (int i = 0; i < 32; ++i) s += w2[j * 32 + i] * s1s[i];
        s2s[j] = fmaxf(s, 0.f);
    }
    __syncthreads();
    if (j < 8) {
        float s = 0.f;
        if (j < 6) {
            s = b3[j];
#pragma unroll
            for (int i = 0; i < 32; ++i) s += w3[j * 32 + i] * s2s[i];
        }
        theta[b * 8 + j] = s;
    }
}

__device__ __forceinline__ void sample_one(const float* __restrict__ x,
                                           int b, int h, int w,
                                           float t0, float t1, float t2,
                                           float t3, float t4, float t5,
                                           float& wgt00, float& wgt10, float& wgt01, float& wgt11,
                                           int& cy0, int& cy1, int& cx0, int& cx1) {
    const float xs = ((float)w - 31.5f) * 0.03125f;
    const float ys = ((float)h - 31.5f) * 0.03125f;
    const float gxn = fmaf(t1, ys, fmaf(t0, xs, t2));
    const float gyn = fmaf(t4, ys, fmaf(t3, xs, t5));
    const float gx = fmaf(gxn, 32.f, 31.5f);   // (gxn+1)*32 - 0.5
    const float gy = fmaf(gyn, 32.f, 31.5f);
    const float x0f = floorf(gx), y0f = floorf(gy);
    const float wx1 = gx - x0f, wx0 = 1.f - wx1;
    const float wy1 = gy - y0f, wy0 = 1.f - wy1;
    const int ix = (int)x0f, iy = (int)y0f;
    const bool vx0 = (ix >= 0) && (ix < 64);
    const bool vx1 = (ix >= -1) && (ix < 63);
    const bool vy0 = (iy >= 0) && (iy < 64);
    const bool vy1 = (iy >= -1) && (iy < 63);
    cx0 = min(max(ix, 0), 63);
    cx1 = min(max(ix + 1, 0), 63);
    cy0 = min(max(iy, 0), 63);
    cy1 = min(max(iy + 1, 0), 63);
    wgt00 = wx0 * wy0 * ((vx0 && vy0) ? 1.f : 0.f);
    wgt10 = wx1 * wy0 * ((vx1 && vy0) ? 1.f : 0.f);
    wgt01 = wx0 * wy1 * ((vx0 && vy1) ? 1.f : 0.f);
    wgt11 = wx1 * wy1 * ((vx1 && vy1) ? 1.f : 0.f);
}

__global__ __launch_bounds__(256) void st_sample(const float* __restrict__ x,
                                                 const float* theta,
                                                 float* out) {
    const int bid = blockIdx.x;
    const int b = bid >> 6;
    const int h = bid & 63;
    const int t = threadIdx.x;
    const int w = t & 63;
    const int c0 = t >> 6;

    const float* tb = theta + b * 8;   // uniform
    const float t0 = tb[0], t1 = tb[1], t2 = tb[2];
    const float t3 = tb[3], t4 = tb[4], t5 = tb[5];

    float w00, w10, w01, w11;
    int cy0, cy1, cx0, cx1;
    sample_one(x, b, h, w, t0, t1, t2, t3, t4, t5, w00, w10, w01, w11, cy0, cy1, cx0, cx1);

    const bool tailblk = (b == 255) && (h >= 32);
    const int r0 = cy0 * 64, r1 = cy1 * 64;

#pragma unroll
    for (int i = 0; i < 8; ++i) {
        const int c = c0 + 4 * i;
        const float* img = x + (((size_t)b * 32 + c) << 12);
        const float v = w00 * img[r0 + cx0] + w10 * img[r0 + cx1]
                      + w01 * img[r1 + cx0] + w11 * img[r1 + cx1];
        if (!(tailblk && c == 31)) {
            __builtin_nontemporal_store(v, &out[(((size_t)b * 32 + c) << 12) + h * 64 + w]);
        }
    }
}

// Last 2048 elements: b=255, c=31, h in [32,64). This region of d_out holds theta,
// so read theta first, sync, then overwrite.
__global__ __launch_bounds__(256) void st_sample_tail(const float* __restrict__ x,
                                                      float* out,
                                                      long long tailstart) {
    const float* tb = out + tailstart + 255 * 8;   // theta[255]
    const float t0 = tb[0], t1 = tb[1], t2 = tb[2];
    const float t3 = tb[3], t4 = tb[4], t5 = tb[5];

    const int t = threadIdx.x;
    float vals[8];
#pragma unroll
    for (int i = 0; i < 8; ++i) {
        const long long e = tailstart + (long long)i * 256 + t;
        const int w = (int)(e & 63);
        const int h = (int)((e >> 6) & 63);
        const int c = (int)((e >> 12) & 31);
        const int b = (int)(e >> 17);
        float w00, w10, w01, w11;
        int cy0, cy1, cx0, cx1;
        sample_one(x, b, h, w, t0, t1, t2, t3, t4, t5, w00, w10, w01, w11, cy0, cy1, cx0, cx1);
        const float* img = x + (((size_t)b * 32 + c) << 12);
        vals[i] = w00 * img[cy0 * 64 + cx0] + w10 * img[cy0 * 64 + cx1]
                + w01 * img[cy1 * 64 + cx0] + w11 * img[cy1 * 64 + cx1];
    }
    __syncthreads();   // all theta reads complete before any write
#pragma unroll
    for (int i = 0; i < 8; ++i) {
        const long long e = tailstart + (long long)i * 256 + t;
        out[e] = vals[i];
    }
}

extern "C" void kernel_launch(void* const* d_in, const int* in_sizes, int n_in,
                              void* d_out, int out_size, void* d_ws, size_t ws_size,
                              hipStream_t stream) {
    const float* x  = (const float*)d_in[0];
    const float* w1 = (const float*)d_in[1];
    const float* b1 = (const float*)d_in[2];
    const float* w2 = (const float*)d_in[3];
    const float* b2 = (const float*)d_in[4];
    const float* w3 = (const float*)d_in[5];
    const float* b3 = (const float*)d_in[6];
    float* out = (float*)d_out;

    const long long tailstart = (long long)out_size - 2048;   // 33554432 - 2048
    float* partial = out;                   // [KG][256][32] = 4 MB, overwritten by st_sample
    float* theta   = out + tailstart;       // [256][8] floats in the tail 2048

    st_lin1<<<dim3(KG, 4), 256, 0, stream>>>(x, w1, partial);
    st_mlp<<<256, 64, 0, stream>>>(partial, b1, w2, b2, w3, b3, theta);
    st_sample<<<256 * 64, 256, 0, stream>>>(x, theta, out);
    st_sample_tail<<<1, 256, 0, stream>>>(x, out, tailstart);
}

// Round 2
// 249.466 us; speedup vs baseline: 1.2700x; 1.2700x over previous
//
#include <hip/hip_runtime.h>

// Spatial Transformer: B=256, C=32, H=W=64. All fp32.
//   k1: LDS-tiled skinny GEMM x[256,131072] @ w1^T[131072,32] -> partial[512][256][32] (d_out head)
//   k2: reduce partials + bias/relu + layer2 + layer3 -> theta[256,8] (d_out tail)
//   k3: affine grid + bilinear sample (all but last 2048 elems)
//   k3tail: last 2048 elems (overlap theta storage; read-then-write)

#define K_TOT 131072        // C*H*W
#define KSPL  512           // k-chunks (grid.x of k1)
#define KC    (K_TOT/KSPL)  // 256 k per block
#define KT    64            // k per LDS tile
#define NT    (KC/KT)       // 4 tiles per block
#define MT    128           // batches per block
#define LDX   (KT+4)        // padded LDS row: 68 floats -> conflict-free reads

__global__ __launch_bounds__(128) void st_lin1(const float* __restrict__ x,
                                               const float* __restrict__ w1,
                                               float* __restrict__ partial) {
    __shared__ float xl[MT][LDX];
    __shared__ float wl[32][LDX];

    const int t  = threadIdx.x;
    const int kc = blockIdx.x;           // 0..511
    const int b0 = blockIdx.y * MT;      // 0 or 128
    const int k0 = kc * KC;

    // staging map: thread t loads row srow (+32p), k offset (t&3)*4 + 16*i
    const int srow = t >> 2;             // 0..31
    const int skc  = (t & 3) * 4;        // 0,4,8,12

    // compute map: b = b0 + bg + 16*bb ; j = jg + 8*jj
    const int bg = t >> 3;               // 0..15 (consecutive rows within wave -> no bank conflict)
    const int jg = t & 7;                // 0..7

    const float* xp = x  + (size_t)(b0 + srow) * K_TOT + k0 + skc;
    const float* wp = w1 + (size_t)srow * K_TOT + k0 + skc;

    float acc[8][4];
#pragma unroll
    for (int bb = 0; bb < 8; ++bb)
#pragma unroll
        for (int jj = 0; jj < 4; ++jj) acc[bb][jj] = 0.f;

    float4 xs[16], ws[4];

#define LOAD_TILE(TL)                                                        \
    {                                                                        \
        const int koff = (TL) * KT;                                          \
        _Pragma("unroll")                                                    \
        for (int p = 0; p < 4; ++p)                                          \
            _Pragma("unroll")                                                \
            for (int i = 0; i < 4; ++i)                                      \
                xs[p * 4 + i] = *(const float4*)(xp + (size_t)p * 32 * K_TOT + koff + 16 * i); \
        _Pragma("unroll")                                                    \
        for (int i = 0; i < 4; ++i)                                          \
            ws[i] = *(const float4*)(wp + koff + 16 * i);                    \
    }

    LOAD_TILE(0)

#pragma unroll
    for (int tl = 0; tl < NT; ++tl) {
        __syncthreads();   // previous tile's readers done
#pragma unroll
        for (int p = 0; p < 4; ++p)
#pragma unroll
            for (int i = 0; i < 4; ++i)
                *(float4*)&xl[srow + 32 * p][skc + 16 * i] = xs[p * 4 + i];
#pragma unroll
        for (int i = 0; i < 4; ++i)
            *(float4*)&wl[srow][skc + 16 * i] = ws[i];
        __syncthreads();

        if (tl + 1 < NT) LOAD_TILE(tl + 1)   // async split: issue next loads before compute

#pragma unroll
        for (int k4 = 0; k4 < KT / 4; ++k4) {
            float4 wv[4];
#pragma unroll
            for (int jj = 0; jj < 4; ++jj)
                wv[jj] = *(const float4*)&wl[jg + 8 * jj][4 * k4];
#pragma unroll
            for (int bb = 0; bb < 8; ++bb) {
                const float4 xv = *(const float4*)&xl[bg + 16 * bb][4 * k4];
#pragma unroll
                for (int jj = 0; jj < 4; ++jj)
                    acc[bb][jj] += xv.x * wv[jj].x + xv.y * wv[jj].y
                                 + xv.z * wv[jj].z + xv.w * wv[jj].w;
            }
        }
    }
#undef LOAD_TILE

    float* po = partial + ((size_t)kc * 256 + b0) * 32;
#pragma unroll
    for (int bb = 0; bb < 8; ++bb)
#pragma unroll
        for (int jj = 0; jj < 4; ++jj)
            po[(bg + 16 * bb) * 32 + jg + 8 * jj] = acc[bb][jj];
}

__global__ __launch_bounds__(256) void st_mlp(const float* __restrict__ partial,
                                              const float* __restrict__ b1,
                                              const float* __restrict__ w2,
                                              const float* __restrict__ b2,
                                              const float* __restrict__ w3,
                                              const float* __restrict__ b3,
                                              float* __restrict__ theta) {
    const int b = blockIdx.x;
    const int t = threadIdx.x;
    const int q = t >> 5;      // 0..7
    const int j = t & 31;

    __shared__ float red[8][32];
    __shared__ float s1s[32];
    __shared__ float s2s[32];

    float s = 0.f;
    for (int kg = q; kg < KSPL; kg += 8)
        s += partial[((size_t)kg * 256 + b) * 32 + j];
    red[q][j] = s;
    __syncthreads();

    if (t < 32) {
        float v = b1[t];
#pragma unroll
        for (int qq = 0; qq < 8; ++qq) v += red[qq][t];
        s1s[t] = fmaxf(v, 0.f);
    }
    __syncthreads();
    if (t < 32) {
        float v = b2[t];
#pragma unroll
        for (int i = 0; i < 32; ++i) v += w2[t * 32 + i] * s1s[i];
        s2s[t] = fmaxf(v, 0.f);
    }
    __syncthreads();
    if (t < 8) {
        float v = 0.f;
        if (t < 6) {
            v = b3[t];
#pragma unroll
            for (int i = 0; i < 32; ++i) v += w3[t * 32 + i] * s2s[i];
        }
        theta[b * 8 + t] = v;
    }
}

__device__ __forceinline__ void sample_one(int h, int w,
                                           float t0, float t1, float t2,
                                           float t3, float t4, float t5,
                                           float& wgt00, float& wgt10, float& wgt01, float& wgt11,
                                           int& cy0, int& cy1, int& cx0, int& cx1) {
    const float xs = ((float)w - 31.5f) * 0.03125f;
    const float ys = ((float)h - 31.5f) * 0.03125f;
    const float gxn = fmaf(t1, ys, fmaf(t0, xs, t2));
    const float gyn = fmaf(t4, ys, fmaf(t3, xs, t5));
    const float gx = fmaf(gxn, 32.f, 31.5f);
    const float gy = fmaf(gyn, 32.f, 31.5f);
    const float x0f = floorf(gx), y0f = floorf(gy);
    const float wx1 = gx - x0f, wx0 = 1.f - wx1;
    const float wy1 = gy - y0f, wy0 = 1.f - wy1;
    const int ix = (int)x0f, iy = (int)y0f;
    const bool vx0 = (ix >= 0) && (ix < 64);
    const bool vx1 = (ix >= -1) && (ix < 63);
    const bool vy0 = (iy >= 0) && (iy < 64);
    const bool vy1 = (iy >= -1) && (iy < 63);
    cx0 = min(max(ix, 0), 63);
    cx1 = min(max(ix + 1, 0), 63);
    cy0 = min(max(iy, 0), 63);
    cy1 = min(max(iy + 1, 0), 63);
    wgt00 = wx0 * wy0 * ((vx0 && vy0) ? 1.f : 0.f);
    wgt10 = wx1 * wy0 * ((vx1 && vy0) ? 1.f : 0.f);
    wgt01 = wx0 * wy1 * ((vx0 && vy1) ? 1.f : 0.f);
    wgt11 = wx1 * wy1 * ((vx1 && vy1) ? 1.f : 0.f);
}

__global__ __launch_bounds__(256) void st_sample(const float* __restrict__ x,
                                                 const float* theta,
                                                 float* out) {
    const int bid = blockIdx.x;
    const int b = bid >> 6;
    const int h = bid & 63;
    const int t = threadIdx.x;
    const int w = t & 63;
    const int c0 = t >> 6;

    const float* tb = theta + b * 8;
    const float t0 = tb[0], t1 = tb[1], t2 = tb[2];
    const float t3 = tb[3], t4 = tb[4], t5 = tb[5];

    float w00, w10, w01, w11;
    int cy0, cy1, cx0, cx1;
    sample_one(h, w, t0, t1, t2, t3, t4, t5, w00, w10, w01, w11, cy0, cy1, cx0, cx1);

    const bool tailblk = (b == 255) && (h >= 32);
    const int r0 = cy0 * 64, r1 = cy1 * 64;

#pragma unroll
    for (int i = 0; i < 8; ++i) {
        const int c = c0 + 4 * i;
        const float* img = x + (((size_t)b * 32 + c) << 12);
        const float v = w00 * img[r0 + cx0] + w10 * img[r0 + cx1]
                      + w01 * img[r1 + cx0] + w11 * img[r1 + cx1];
        if (!(tailblk && c == 31)) {
            __builtin_nontemporal_store(v, &out[(((size_t)b * 32 + c) << 12) + h * 64 + w]);
        }
    }
}

// Last 2048 elements: b=255, c=31, h in [32,64). This region of d_out holds theta:
// read theta first, sync, then overwrite.
__global__ __launch_bounds__(256) void st_sample_tail(const float* __restrict__ x,
                                                      float* out,
                                                      long long tailstart) {
    const float* tb = out + tailstart + 255 * 8;
    const float t0 = tb[0], t1 = tb[1], t2 = tb[2];
    const float t3 = tb[3], t4 = tb[4], t5 = tb[5];

    const int t = threadIdx.x;
    float vals[8];
#pragma unroll
    for (int i = 0; i < 8; ++i) {
        const long long e = tailstart + (long long)i * 256 + t;
        const int w = (int)(e & 63);
        const int h = (int)((e >> 6) & 63);
        const int c = (int)((e >> 12) & 31);
        const int b = (int)(e >> 17);
        float w00, w10, w01, w11;
        int cy0, cy1, cx0, cx1;
        sample_one(h, w, t0, t1, t2, t3, t4, t5, w00, w10, w01, w11, cy0, cy1, cx0, cx1);
        const float* img = x + (((size_t)b * 32 + c) << 12);
        vals[i] = w00 * img[cy0 * 64 + cx0] + w10 * img[cy0 * 64 + cx1]
                + w01 * img[cy1 * 64 + cx0] + w11 * img[cy1 * 64 + cx1];
    }
    __syncthreads();
#pragma unroll
    for (int i = 0; i < 8; ++i) {
        const long long e = tailstart + (long long)i * 256 + t;
        out[e] = vals[i];
    }
}

extern "C" void kernel_launch(void* const* d_in, const int* in_sizes, int n_in,
                              void* d_out, int out_size, void* d_ws, size_t ws_size,
                              hipStream_t stream) {
    const float* x  = (const float*)d_in[0];
    const float* w1 = (const float*)d_in[1];
    const float* b1 = (const float*)d_in[2];
    const float* w2 = (const float*)d_in[3];
    const float* b2 = (const float*)d_in[4];
    const float* w3 = (const float*)d_in[5];
    const float* b3 = (const float*)d_in[6];
    float* out = (float*)d_out;

    const long long tailstart = (long long)out_size - 2048;
    float* partial = out;                   // [KSPL][256][32] = 16.8 MB, overwritten by st_sample
    float* theta   = out + tailstart;       // [256][8] in the tail 2048

    st_lin1<<<dim3(KSPL, 2), 128, 0, stream>>>(x, w1, partial);
    st_mlp<<<256, 256, 0, stream>>>(partial, b1, w2, b2, w3, b3, theta);
    st_sample<<<256 * 64, 256, 0, stream>>>(x, theta, out);
    st_sample_tail<<<1, 256, 0, stream>>>(x, out, tailstart);
}

// Round 3
// 149.282 us; speedup vs baseline: 2.1223x; 1.6711x over previous
//
#include <hip/hip_runtime.h>

// Spatial Transformer: B=256, C=32, H=W=64. All fp32.
//   k1: barrier-free streaming GEMM x[256,131072] @ w1^T -> partial[128][256][32] (d_out head)
//       lane=k layout, x global->reg once, w streamed from L2 (XCD-swizzled), shfl butterfly reduce
//   k2: reduce partials + bias/relu + layer2 + layer3 -> theta[256,8] (d_out tail)
//   k3: affine grid + bilinear sample (all but last 2048 elems)
//   k3tail: last 2048 elems (overlap theta storage; read-then-write)

#define K_TOT 131072
#define KCH_N 128           // number of k-chunks (grid: KCH_N * 16 bgroups = 2048 blocks)
#define KC    1024          // k per block
#define NP    4             // passes of 256 k per block

__global__ __launch_bounds__(256) void st_lin1(const float* __restrict__ x,
                                               const float* __restrict__ w1,
                                               float* __restrict__ partial) {
    // XCD swizzle: give each XCD 16 consecutive kchunks so its w working set (2 MB) is L2-resident.
    const int slot   = blockIdx.x;        // 0..2047
    const int xcd    = slot & 7;
    const int s      = slot >> 3;         // 0..255
    const int kchunk = xcd * 16 + (s >> 4);   // 0..127
    const int bgroup = s & 15;                // 0..15

    const int t    = threadIdx.x;
    const int kq   = t & 63;
    const int bsel = (t >> 6) & 1;        // wave-uniform
    const int jsel = t >> 7;              // wave-uniform

    const int bb0 = bgroup * 16 + bsel * 8;   // 8 batches per thread
    const int j0  = jsel * 16;                // 16 outputs per thread
    const int k0  = kchunk * KC;

    const float* xp = x  + (size_t)bb0 * K_TOT + k0 + 4 * kq;
    const float* wp = w1 + (size_t)j0  * K_TOT + k0 + 4 * kq;

    float acc[128];   // [b][j] flattened, static indexing only
#pragma unroll
    for (int i = 0; i < 128; ++i) acc[i] = 0.f;

#define LOADX(DST, P)                                                         \
    _Pragma("unroll")                                                         \
    for (int b = 0; b < 8; ++b)                                               \
        DST[b] = *(const float4*)(xp + (size_t)b * K_TOT + (P) * 256);

#define COMPUTE(XV, P)                                                        \
    _Pragma("unroll")                                                         \
    for (int j = 0; j < 16; ++j) {                                            \
        const float4 wv = *(const float4*)(wp + (size_t)j * K_TOT + (P) * 256); \
        _Pragma("unroll")                                                     \
        for (int b = 0; b < 8; ++b)                                           \
            acc[b * 16 + j] += XV[b].x * wv.x + XV[b].y * wv.y                \
                             + XV[b].z * wv.z + XV[b].w * wv.w;               \
    }

    float4 xa[8], xb[8];
    LOADX(xa, 0)
    for (int p = 0; p < NP; p += 2) {         // NP even; register-dep pipelined, no barriers
        if (p + 1 < NP) LOADX(xb, p + 1)
        COMPUTE(xa, p)
        if (p + 2 < NP) LOADX(xa, p + 2)
        if (p + 1 < NP) COMPUTE(xb, p + 1)
    }
#undef LOADX
#undef COMPUTE

    // Halving butterfly across the wave's 64 lanes (lanes = k-slices):
    // 128 partials/lane -> 2 fully-reduced outputs/lane. 126 shfl + 126 add.
    const int lane = t & 63;
#define RSTEP(VIN, VOUT, N, M)                                                \
    _Pragma("unroll")                                                         \
    for (int i = 0; i < (N) / 2; ++i) {                                       \
        const bool hi = (lane & (M)) != 0;                                    \
        const float send = hi ? VIN[i] : VIN[i + (N) / 2];                    \
        const float r = __shfl_xor(send, (M), 64);                            \
        VOUT[i] = (hi ? VIN[i + (N) / 2] : VIN[i]) + r;                       \
    }
    float v64[64]; RSTEP(acc, v64, 128, 1)
    float v32[32]; RSTEP(v64, v32, 64, 2)
    float v16[16]; RSTEP(v32, v16, 32, 4)
    float v8[8];   RSTEP(v16, v8, 16, 8)
    float v4[4];   RSTEP(v8,  v4, 8, 16)
    float v2[2];   RSTEP(v4,  v2, 4, 32)
#undef RSTEP

    // v2[r] = full sum of acc index: r | lane-bit permutation (each bit used once -> bijection)
#pragma unroll
    for (int r = 0; r < 2; ++r) {
        const int idx = r | (((lane >> 5) & 1) << 1) | (((lane >> 4) & 1) << 2)
                          | (((lane >> 3) & 1) << 3) | (((lane >> 2) & 1) << 4)
                          | (((lane >> 1) & 1) << 5) | ((lane & 1) << 6);
        const int bl = idx >> 4;      // 0..7
        const int jl = idx & 15;      // 0..15
        partial[((size_t)kchunk * 256 + bb0 + bl) * 32 + j0 + jl] = v2[r];
    }
}

__global__ __launch_bounds__(256) void st_mlp(const float* __restrict__ partial,
                                              const float* __restrict__ b1,
                                              const float* __restrict__ w2,
                                              const float* __restrict__ b2,
                                              const float* __restrict__ w3,
                                              const float* __restrict__ b3,
                                              float* __restrict__ theta) {
    const int b = blockIdx.x;
    const int t = threadIdx.x;
    const int q = t >> 5;      // 0..7
    const int j = t & 31;

    __shared__ float red[8][32];
    __shared__ float s1s[32];
    __shared__ float s2s[32];

    float s = 0.f;
    for (int kg = q; kg < KCH_N; kg += 8)
        s += partial[((size_t)kg * 256 + b) * 32 + j];
    red[q][j] = s;
    __syncthreads();

    if (t < 32) {
        float v = b1[t];
#pragma unroll
        for (int qq = 0; qq < 8; ++qq) v += red[qq][t];
        s1s[t] = fmaxf(v, 0.f);
    }
    __syncthreads();
    if (t < 32) {
        float v = b2[t];
#pragma unroll
        for (int i = 0; i < 32; ++i) v += w2[t * 32 + i] * s1s[i];
        s2s[t] = fmaxf(v, 0.f);
    }
    __syncthreads();
    if (t < 8) {
        float v = 0.f;
        if (t < 6) {
            v = b3[t];
#pragma unroll
            for (int i = 0; i < 32; ++i) v += w3[t * 32 + i] * s2s[i];
        }
        theta[b * 8 + t] = v;
    }
}

__device__ __forceinline__ void sample_one(int h, int w,
                                           float t0, float t1, float t2,
                                           float t3, float t4, float t5,
                                           float& wgt00, float& wgt10, float& wgt01, float& wgt11,
                                           int& cy0, int& cy1, int& cx0, int& cx1) {
    const float xs = ((float)w - 31.5f) * 0.03125f;
    const float ys = ((float)h - 31.5f) * 0.03125f;
    const float gxn = fmaf(t1, ys, fmaf(t0, xs, t2));
    const float gyn = fmaf(t4, ys, fmaf(t3, xs, t5));
    const float gx = fmaf(gxn, 32.f, 31.5f);
    const float gy = fmaf(gyn, 32.f, 31.5f);
    const float x0f = floorf(gx), y0f = floorf(gy);
    const float wx1 = gx - x0f, wx0 = 1.f - wx1;
    const float wy1 = gy - y0f, wy0 = 1.f - wy1;
    const int ix = (int)x0f, iy = (int)y0f;
    const bool vx0 = (ix >= 0) && (ix < 64);
    const bool vx1 = (ix >= -1) && (ix < 63);
    const bool vy0 = (iy >= 0) && (iy < 64);
    const bool vy1 = (iy >= -1) && (iy < 63);
    cx0 = min(max(ix, 0), 63);
    cx1 = min(max(ix + 1, 0), 63);
    cy0 = min(max(iy, 0), 63);
    cy1 = min(max(iy + 1, 0), 63);
    wgt00 = wx0 * wy0 * ((vx0 && vy0) ? 1.f : 0.f);
    wgt10 = wx1 * wy0 * ((vx1 && vy0) ? 1.f : 0.f);
    wgt01 = wx0 * wy1 * ((vx0 && vy1) ? 1.f : 0.f);
    wgt11 = wx1 * wy1 * ((vx1 && vy1) ? 1.f : 0.f);
}

__global__ __launch_bounds__(256) void st_sample(const float* __restrict__ x,
                                                 const float* theta,
                                                 float* out) {
    const int bid = blockIdx.x;
    const int b = bid >> 6;
    const int h = bid & 63;
    const int t = threadIdx.x;
    const int w = t & 63;
    const int c0 = t >> 6;

    const float* tb = theta + b * 8;
    const float t0 = tb[0], t1 = tb[1], t2 = tb[2];
    const float t3 = tb[3], t4 = tb[4], t5 = tb[5];

    float w00, w10, w01, w11;
    int cy0, cy1, cx0, cx1;
    sample_one(h, w, t0, t1, t2, t3, t4, t5, w00, w10, w01, w11, cy0, cy1, cx0, cx1);

    const bool tailblk = (b == 255) && (h >= 32);
    const int r0 = cy0 * 64, r1 = cy1 * 64;

#pragma unroll
    for (int i = 0; i < 8; ++i) {
        const int c = c0 + 4 * i;
        const float* img = x + (((size_t)b * 32 + c) << 12);
        const float v = w00 * img[r0 + cx0] + w10 * img[r0 + cx1]
                      + w01 * img[r1 + cx0] + w11 * img[r1 + cx1];
        if (!(tailblk && c == 31)) {
            __builtin_nontemporal_store(v, &out[(((size_t)b * 32 + c) << 12) + h * 64 + w]);
        }
    }
}

// Last 2048 elements: b=255, c=31, h in [32,64). This region of d_out holds theta:
// read theta first, sync, then overwrite.
__global__ __launch_bounds__(256) void st_sample_tail(const float* __restrict__ x,
                                                      float* out,
                                                      long long tailstart) {
    const float* tb = out + tailstart + 255 * 8;
    const float t0 = tb[0], t1 = tb[1], t2 = tb[2];
    const float t3 = tb[3], t4 = tb[4], t5 = tb[5];

    const int t = threadIdx.x;
    float vals[8];
#pragma unroll
    for (int i = 0; i < 8; ++i) {
        const long long e = tailstart + (long long)i * 256 + t;
        const int w = (int)(e & 63);
        const int h = (int)((e >> 6) & 63);
        const int c = (int)((e >> 12) & 31);
        const int b = (int)(e >> 17);
        float w00, w10, w01, w11;
        int cy0, cy1, cx0, cx1;
        sample_one(h, w, t0, t1, t2, t3, t4, t5, w00, w10, w01, w11, cy0, cy1, cx0, cx1);
        const float* img = x + (((size_t)b * 32 + c) << 12);
        vals[i] = w00 * img[cy0 * 64 + cx0] + w10 * img[cy0 * 64 + cx1]
                + w01 * img[cy1 * 64 + cx0] + w11 * img[cy1 * 64 + cx1];
    }
    __syncthreads();
#pragma unroll
    for (int i = 0; i < 8; ++i) {
        const long long e = tailstart + (long long)i * 256 + t;
        out[e] = vals[i];
    }
}

extern "C" void kernel_launch(void* const* d_in, const int* in_sizes, int n_in,
                              void* d_out, int out_size, void* d_ws, size_t ws_size,
                              hipStream_t stream) {
    const float* x  = (const float*)d_in[0];
    const float* w1 = (const float*)d_in[1];
    const float* b1 = (const float*)d_in[2];
    const float* w2 = (const float*)d_in[3];
    const float* b2 = (const float*)d_in[4];
    const float* w3 = (const float*)d_in[5];
    const float* b3 = (const float*)d_in[6];
    float* out = (float*)d_out;

    const long long tailstart = (long long)out_size - 2048;
    float* partial = out;                   // [KCH_N][256][32] = 4 MB, overwritten by st_sample
    float* theta   = out + tailstart;       // [256][8] in the tail 2048

    st_lin1<<<KCH_N * 16, 256, 0, stream>>>(x, w1, partial);
    st_mlp<<<256, 256, 0, stream>>>(partial, b1, w2, b2, w3, b3, theta);
    st_sample<<<256 * 64, 256, 0, stream>>>(x, theta, out);
    st_sample_tail<<<1, 256, 0, stream>>>(x, out, tailstart);
}

// Round 4
// 127.805 us; speedup vs baseline: 2.4789x; 1.1681x over previous
//
#include <hip/hip_runtime.h>
#include <hip/hip_bf16.h>

// Spatial Transformer: B=256, C=32, H=W=64. All fp32 in/out.
//   k1: bf16 MFMA k-split GEMM x[256,131072] @ w1^T -> partial[512][256][32] (d_out head, fp32)
//       direct global->VGPR fragment loads, no LDS, no barriers; accuracy: bf16 inputs, fp32 acc
//   k2: reduce partials + bias/relu + layer2 + layer3 -> theta[256,8] (d_out tail)
//   k3: affine grid + bilinear sample (all but last 2048 elems)
//   k3tail: last 2048 elems (overlap theta storage; read-then-write)

#define K_TOT 131072
#define KC    256           // k per block
#define KSPL  (K_TOT/KC)    // 512 k-chunks

typedef short s16x8 __attribute__((ext_vector_type(8)));   // 8 bf16 in 4 VGPRs
typedef float f32x4 __attribute__((ext_vector_type(4)));

__device__ __forceinline__ short f2bf(float f) {
    return __builtin_bit_cast(short, __float2bfloat16(f));  // RNE; compiler may fuse to v_cvt_pk
}

__device__ __forceinline__ s16x8 cvt8(float4 a, float4 b) {
    s16x8 r;
    r[0] = f2bf(a.x); r[1] = f2bf(a.y); r[2] = f2bf(a.z); r[3] = f2bf(a.w);
    r[4] = f2bf(b.x); r[5] = f2bf(b.y); r[6] = f2bf(b.z); r[7] = f2bf(b.w);
    return r;
}

__global__ __launch_bounds__(256) void st_lin1(const float* __restrict__ x,
                                               const float* __restrict__ w1,
                                               float* __restrict__ partial) {
    // XCD swizzle: contiguous kchunk range per XCD -> w slice (~2.1 MB) L2-resident.
    const int bid = blockIdx.x;            // 0..2047
    const int xcd = bid & 7;
    const int r   = bid >> 3;              // 0..255
    const int kc  = xcd * 64 + (r >> 2);   // 0..511
    const int bg  = r & 3;                 // 0..3

    const int t    = threadIdx.x;
    const int wv   = t >> 6;               // wave 0..3 -> 16-batch tile
    const int lane = t & 63;
    const int m    = lane & 15;            // A: row (b); B: col (j)
    const int kb   = lane >> 4;            // k-block 0..3 (8 k each)

    const int b0 = bg * 64 + wv * 16;
    const long long k0 = (long long)kc * KC + kb * 8;

    const float* xp  = x  + (size_t)(b0 + m) * K_TOT + k0;
    const float* wp0 = w1 + (size_t)m        * K_TOT + k0;
    const float* wp1 = w1 + (size_t)(16 + m) * K_TOT + k0;

    f32x4 acc0 = {0.f, 0.f, 0.f, 0.f};
    f32x4 acc1 = {0.f, 0.f, 0.f, 0.f};

#pragma unroll
    for (int s = 0; s < KC / 32; ++s) {
        const int o = s * 32;
        const float4 a0  = *(const float4*)(xp  + o);
        const float4 a1  = *(const float4*)(xp  + o + 4);
        const float4 b00 = *(const float4*)(wp0 + o);
        const float4 b01 = *(const float4*)(wp0 + o + 4);
        const float4 b10 = *(const float4*)(wp1 + o);
        const float4 b11 = *(const float4*)(wp1 + o + 4);
        const s16x8 af  = cvt8(a0,  a1);
        const s16x8 bf0 = cvt8(b00, b01);
        const s16x8 bf1 = cvt8(b10, b11);
        acc0 = __builtin_amdgcn_mfma_f32_16x16x32_bf16(af, bf0, acc0, 0, 0, 0);
        acc1 = __builtin_amdgcn_mfma_f32_16x16x32_bf16(af, bf1, acc1, 0, 0, 0);
    }

    // C/D layout: col = lane&15 (j), row = (lane>>4)*4 + reg (b within 16-tile)
    float* po = partial + ((size_t)kc * 256 + b0 + kb * 4) * 32 + m;
#pragma unroll
    for (int rr = 0; rr < 4; ++rr) {
        po[(size_t)rr * 32]      = acc0[rr];   // j = m
        po[(size_t)rr * 32 + 16] = acc1[rr];   // j = 16 + m
    }
}

__global__ __launch_bounds__(256) void st_mlp(const float* __restrict__ partial,
                                              const float* __restrict__ b1,
                                              const float* __restrict__ w2,
                                              const float* __restrict__ b2,
                                              const float* __restrict__ w3,
                                              const float* __restrict__ b3,
                                              float* __restrict__ theta) {
    const int b = blockIdx.x;
    const int t = threadIdx.x;
    const int q = t >> 5;      // 0..7
    const int j = t & 31;

    __shared__ float red[8][32];
    __shared__ float s1s[32];
    __shared__ float s2s[32];

    float s = 0.f;
    for (int kg = q; kg < KSPL; kg += 8)
        s += partial[((size_t)kg * 256 + b) * 32 + j];
    red[q][j] = s;
    __syncthreads();

    if (t < 32) {
        float v = b1[t];
#pragma unroll
        for (int qq = 0; qq < 8; ++qq) v += red[qq][t];
        s1s[t] = fmaxf(v, 0.f);
    }
    __syncthreads();
    if (t < 32) {
        float v = b2[t];
#pragma unroll
        for (int i = 0; i < 32; ++i) v += w2[t * 32 + i] * s1s[i];
        s2s[t] = fmaxf(v, 0.f);
    }
    __syncthreads();
    if (t < 8) {
        float v = 0.f;
        if (t < 6) {
            v = b3[t];
#pragma unroll
            for (int i = 0; i < 32; ++i) v += w3[t * 32 + i] * s2s[i];
        }
        theta[b * 8 + t] = v;
    }
}

__device__ __forceinline__ void sample_one(int h, int w,
                                           float t0, float t1, float t2,
                                           float t3, float t4, float t5,
                                           float& wgt00, float& wgt10, float& wgt01, float& wgt11,
                                           int& cy0, int& cy1, int& cx0, int& cx1) {
    const float xs = ((float)w - 31.5f) * 0.03125f;
    const float ys = ((float)h - 31.5f) * 0.03125f;
    const float gxn = fmaf(t1, ys, fmaf(t0, xs, t2));
    const float gyn = fmaf(t4, ys, fmaf(t3, xs, t5));
    const float gx = fmaf(gxn, 32.f, 31.5f);
    const float gy = fmaf(gyn, 32.f, 31.5f);
    const float x0f = floorf(gx), y0f = floorf(gy);
    const float wx1 = gx - x0f, wx0 = 1.f - wx1;
    const float wy1 = gy - y0f, wy0 = 1.f - wy1;
    const int ix = (int)x0f, iy = (int)y0f;
    const bool vx0 = (ix >= 0) && (ix < 64);
    const bool vx1 = (ix >= -1) && (ix < 63);
    const bool vy0 = (iy >= 0) && (iy < 64);
    const bool vy1 = (iy >= -1) && (iy < 63);
    cx0 = min(max(ix, 0), 63);
    cx1 = min(max(ix + 1, 0), 63);
    cy0 = min(max(iy, 0), 63);
    cy1 = min(max(iy + 1, 0), 63);
    wgt00 = wx0 * wy0 * ((vx0 && vy0) ? 1.f : 0.f);
    wgt10 = wx1 * wy0 * ((vx1 && vy0) ? 1.f : 0.f);
    wgt01 = wx0 * wy1 * ((vx0 && vy1) ? 1.f : 0.f);
    wgt11 = wx1 * wy1 * ((vx1 && vy1) ? 1.f : 0.f);
}

__global__ __launch_bounds__(256) void st_sample(const float* __restrict__ x,
                                                 const float* theta,
                                                 float* out) {
    const int bid = blockIdx.x;
    const int b = bid >> 6;
    const int h = bid & 63;
    const int t = threadIdx.x;
    const int w = t & 63;
    const int c0 = t >> 6;

    const float* tb = theta + b * 8;
    const float t0 = tb[0], t1 = tb[1], t2 = tb[2];
    const float t3 = tb[3], t4 = tb[4], t5 = tb[5];

    float w00, w10, w01, w11;
    int cy0, cy1, cx0, cx1;
    sample_one(h, w, t0, t1, t2, t3, t4, t5, w00, w10, w01, w11, cy0, cy1, cx0, cx1);

    const bool tailblk = (b == 255) && (h >= 32);
    const int r0 = cy0 * 64, r1 = cy1 * 64;

#pragma unroll
    for (int i = 0; i < 8; ++i) {
        const int c = c0 + 4 * i;
        const float* img = x + (((size_t)b * 32 + c) << 12);
        const float v = w00 * img[r0 + cx0] + w10 * img[r0 + cx1]
                      + w01 * img[r1 + cx0] + w11 * img[r1 + cx1];
        if (!(tailblk && c == 31)) {
            __builtin_nontemporal_store(v, &out[(((size_t)b * 32 + c) << 12) + h * 64 + w]);
        }
    }
}

// Last 2048 elements: b=255, c=31, h in [32,64). This region of d_out holds theta:
// read theta first, sync, then overwrite.
__global__ __launch_bounds__(256) void st_sample_tail(const float* __restrict__ x,
                                                      float* out,
                                                      long long tailstart) {
    const float* tb = out + tailstart + 255 * 8;
    const float t0 = tb[0], t1 = tb[1], t2 = tb[2];
    const float t3 = tb[3], t4 = tb[4], t5 = tb[5];

    const int t = threadIdx.x;
    float vals[8];
#pragma unroll
    for (int i = 0; i < 8; ++i) {
        const long long e = tailstart + (long long)i * 256 + t;
        const int w = (int)(e & 63);
        const int h = (int)((e >> 6) & 63);
        const int c = (int)((e >> 12) & 31);
        const int b = (int)(e >> 17);
        float w00, w10, w01, w11;
        int cy0, cy1, cx0, cx1;
        sample_one(h, w, t0, t1, t2, t3, t4, t5, w00, w10, w01, w11, cy0, cy1, cx0, cx1);
        const float* img = x + (((size_t)b * 32 + c) << 12);
        vals[i] = w00 * img[cy0 * 64 + cx0] + w10 * img[cy0 * 64 + cx1]
                + w01 * img[cy1 * 64 + cx0] + w11 * img[cy1 * 64 + cx1];
    }
    __syncthreads();
#pragma unroll
    for (int i = 0; i < 8; ++i) {
        const long long e = tailstart + (long long)i * 256 + t;
        out[e] = vals[i];
    }
}

extern "C" void kernel_launch(void* const* d_in, const int* in_sizes, int n_in,
                              void* d_out, int out_size, void* d_ws, size_t ws_size,
                              hipStream_t stream) {
    const float* x  = (const float*)d_in[0];
    const float* w1 = (const float*)d_in[1];
    const float* b1 = (const float*)d_in[2];
    const float* w2 = (const float*)d_in[3];
    const float* b2 = (const float*)d_in[4];
    const float* w3 = (const float*)d_in[5];
    const float* b3 = (const float*)d_in[6];
    float* out = (float*)d_out;

    const long long tailstart = (long long)out_size - 2048;
    float* partial = out;                   // [KSPL][256][32] = 16 MB, overwritten by st_sample
    float* theta   = out + tailstart;       // [256][8] in the tail 2048

    st_lin1<<<KSPL * 4, 256, 0, stream>>>(x, w1, partial);
    st_mlp<<<256, 256, 0, stream>>>(partial, b1, w2, b2, w3, b3, theta);
    st_sample<<<256 * 64, 256, 0, stream>>>(x, theta, out);
    st_sample_tail<<<1, 256, 0, stream>>>(x, out, tailstart);
}

// Round 5
// 103.934 us; speedup vs baseline: 3.0483x; 1.2297x over previous
//
#include <hip/hip_runtime.h>
#include <hip/hip_bf16.h>

// Spatial Transformer: B=256, C=32, H=W=64. All fp32 in/out.
//   k1: bf16 MFMA k-split GEMM x[256,131072] @ w1^T -> partial[256][512][32] (d_out head, fp32)
//       wave tile 32b x 32j (4 MFMA / 8 loads), direct global->VGPR frags, no LDS/barriers
//   k2: reduce partials (contiguous stream) + bias/relu + layer2 + layer3 -> theta[256,8]
//   k3: affine grid + bilinear sample (all but last 2048 elems)
//   k3tail: last 2048 elems (overlap theta storage; read-then-write)

#define K_TOT 131072
#define KC    256           // k per block
#define KSPL  (K_TOT/KC)    // 512 k-chunks; partial layout [b][kc][j]

typedef short s16x8 __attribute__((ext_vector_type(8)));   // 8 bf16 in 4 VGPRs
typedef float f32x4 __attribute__((ext_vector_type(4)));

__device__ __forceinline__ short f2bf(float f) {
    return __builtin_bit_cast(short, __float2bfloat16(f));  // RNE scalar cast; compiler fuses
}

__device__ __forceinline__ s16x8 cvt8(float4 a, float4 b) {
    s16x8 r;
    r[0] = f2bf(a.x); r[1] = f2bf(a.y); r[2] = f2bf(a.z); r[3] = f2bf(a.w);
    r[4] = f2bf(b.x); r[5] = f2bf(b.y); r[6] = f2bf(b.z); r[7] = f2bf(b.w);
    return r;
}

__global__ __launch_bounds__(256) void st_lin1(const float* __restrict__ x,
                                               const float* __restrict__ w1,
                                               float* __restrict__ partial) {
    // XCD swizzle: contiguous kc range per XCD -> per-XCD w working set 2 MB (L2-resident).
    const int bid = blockIdx.x;            // 0..1023
    const int xcd = bid & 7;
    const int s   = bid >> 3;              // 0..127
    const int kc  = xcd * 64 + (s >> 1);   // 0..511
    const int bg  = s & 1;                 // 0..1

    const int t    = threadIdx.x;
    const int wv   = t >> 6;               // wave 0..3 -> 32-batch subtile
    const int lane = t & 63;
    const int m    = lane & 15;            // A: row within 16-tile; B: col (j)
    const int kb   = lane >> 4;            // k-block 0..3 (8 k each)

    const int b0 = bg * 128 + wv * 32;
    const long long k0 = (long long)kc * KC + kb * 8;

    const float* xp0 = x  + (size_t)(b0 + m)      * K_TOT + k0;
    const float* xp1 = x  + (size_t)(b0 + 16 + m) * K_TOT + k0;
    const float* wp0 = w1 + (size_t)m             * K_TOT + k0;   // j = m
    const float* wp1 = w1 + (size_t)(16 + m)      * K_TOT + k0;   // j = 16+m

    f32x4 acc00 = {0.f,0.f,0.f,0.f}, acc01 = {0.f,0.f,0.f,0.f};
    f32x4 acc10 = {0.f,0.f,0.f,0.f}, acc11 = {0.f,0.f,0.f,0.f};

#pragma unroll
    for (int ss = 0; ss < KC / 32; ++ss) {
        const int o = ss * 32;
        const float4 a00 = *(const float4*)(xp0 + o);
        const float4 a01 = *(const float4*)(xp0 + o + 4);
        const float4 a10 = *(const float4*)(xp1 + o);
        const float4 a11 = *(const float4*)(xp1 + o + 4);
        const float4 b00 = *(const float4*)(wp0 + o);
        const float4 b01 = *(const float4*)(wp0 + o + 4);
        const float4 b10 = *(const float4*)(wp1 + o);
        const float4 b11 = *(const float4*)(wp1 + o + 4);
        const s16x8 af0 = cvt8(a00, a01);
        const s16x8 af1 = cvt8(a10, a11);
        const s16x8 bf0 = cvt8(b00, b01);
        const s16x8 bf1 = cvt8(b10, b11);
        acc00 = __builtin_amdgcn_mfma_f32_16x16x32_bf16(af0, bf0, acc00, 0, 0, 0);
        acc01 = __builtin_amdgcn_mfma_f32_16x16x32_bf16(af0, bf1, acc01, 0, 0, 0);
        acc10 = __builtin_amdgcn_mfma_f32_16x16x32_bf16(af1, bf0, acc10, 0, 0, 0);
        acc11 = __builtin_amdgcn_mfma_f32_16x16x32_bf16(af1, bf1, acc11, 0, 0, 0);
    }

    // C/D layout: col(j) = lane&15, row(b within 16-tile) = kb*4 + reg.
    // partial[b][kc][j], strideB = KSPL*32 floats.
    const size_t strideB = (size_t)KSPL * 32;
    float* p0 = partial + (size_t)(b0 + kb * 4) * strideB + (size_t)kc * 32 + m;
#pragma unroll
    for (int rr = 0; rr < 4; ++rr) {
        p0[(size_t)rr * strideB]             = acc00[rr];   // b=b0+kb*4+rr,    j=m
        p0[(size_t)rr * strideB + 16]        = acc01[rr];   //                  j=16+m
        p0[(size_t)(16 + rr) * strideB]      = acc10[rr];   // b=b0+16+kb*4+rr, j=m
        p0[(size_t)(16 + rr) * strideB + 16] = acc11[rr];   //                  j=16+m
    }
}

__global__ __launch_bounds__(256) void st_mlp(const float* __restrict__ partial,
                                              const float* __restrict__ b1,
                                              const float* __restrict__ w2,
                                              const float* __restrict__ b2,
                                              const float* __restrict__ w3,
                                              const float* __restrict__ b3,
                                              float* __restrict__ theta) {
    const int b = blockIdx.x;
    const int t = threadIdx.x;
    const float* pb = partial + (size_t)b * KSPL * 32;   // 64 KB contiguous per block

    // Coalesced contiguous stream: thread t reads float4 at (i*256+t)*4.
    // Its j-quad is constant: j0 = (4t)&31 (since 256*4 % 32 == 0).
    float4 v = {0.f, 0.f, 0.f, 0.f};
#pragma unroll
    for (int i = 0; i < 16; ++i) {
        const float4 u = *(const float4*)(pb + (size_t)(i * 256 + t) * 4);
        v.x += u.x; v.y += u.y; v.z += u.z; v.w += u.w;
    }

    __shared__ float4 ld[256];
    __shared__ float s1s[32];
    __shared__ float s2s[32];
    ld[t] = v;
    __syncthreads();
    // Tree-reduce with offsets that are multiples of 8 -> merges only same j-quad classes.
#pragma unroll
    for (int off = 128; off >= 8; off >>= 1) {
        if (t < off) {
            float4 a = ld[t];
            const float4 c = ld[t + off];
            a.x += c.x; a.y += c.y; a.z += c.z; a.w += c.w;
            ld[t] = a;
        }
        __syncthreads();
    }
    if (t < 8) {   // thread t holds j-quad 4t..4t+3
        const float4 q = ld[t];
        s1s[4 * t + 0] = fmaxf(q.x + b1[4 * t + 0], 0.f);
        s1s[4 * t + 1] = fmaxf(q.y + b1[4 * t + 1], 0.f);
        s1s[4 * t + 2] = fmaxf(q.z + b1[4 * t + 2], 0.f);
        s1s[4 * t + 3] = fmaxf(q.w + b1[4 * t + 3], 0.f);
    }
    __syncthreads();
    if (t < 32) {
        float vv = b2[t];
#pragma unroll
        for (int i = 0; i < 32; ++i) vv += w2[t * 32 + i] * s1s[i];
        s2s[t] = fmaxf(vv, 0.f);
    }
    __syncthreads();
    if (t < 8) {
        float vv = 0.f;
        if (t < 6) {
            vv = b3[t];
#pragma unroll
            for (int i = 0; i < 32; ++i) vv += w3[t * 32 + i] * s2s[i];
        }
        theta[b * 8 + t] = vv;
    }
}

__device__ __forceinline__ void sample_one(int h, int w,
                                           float t0, float t1, float t2,
                                           float t3, float t4, float t5,
                                           float& wgt00, float& wgt10, float& wgt01, float& wgt11,
                                           int& cy0, int& cy1, int& cx0, int& cx1) {
    const float xs = ((float)w - 31.5f) * 0.03125f;
    const float ys = ((float)h - 31.5f) * 0.03125f;
    const float gxn = fmaf(t1, ys, fmaf(t0, xs, t2));
    const float gyn = fmaf(t4, ys, fmaf(t3, xs, t5));
    const float gx = fmaf(gxn, 32.f, 31.5f);
    const float gy = fmaf(gyn, 32.f, 31.5f);
    const float x0f = floorf(gx), y0f = floorf(gy);
    const float wx1 = gx - x0f, wx0 = 1.f - wx1;
    const float wy1 = gy - y0f, wy0 = 1.f - wy1;
    const int ix = (int)x0f, iy = (int)y0f;
    const bool vx0 = (ix >= 0) && (ix < 64);
    const bool vx1 = (ix >= -1) && (ix < 63);
    const bool vy0 = (iy >= 0) && (iy < 64);
    const bool vy1 = (iy >= -1) && (iy < 63);
    cx0 = min(max(ix, 0), 63);
    cx1 = min(max(ix + 1, 0), 63);
    cy0 = min(max(iy, 0), 63);
    cy1 = min(max(iy + 1, 0), 63);
    wgt00 = wx0 * wy0 * ((vx0 && vy0) ? 1.f : 0.f);
    wgt10 = wx1 * wy0 * ((vx1 && vy0) ? 1.f : 0.f);
    wgt01 = wx0 * wy1 * ((vx0 && vy1) ? 1.f : 0.f);
    wgt11 = wx1 * wy1 * ((vx1 && vy1) ? 1.f : 0.f);
}

__global__ __launch_bounds__(256) void st_sample(const float* __restrict__ x,
                                                 const float* theta,
                                                 float* out) {
    const int bid = blockIdx.x;
    const int b = bid >> 6;
    const int h = bid & 63;
    const int t = threadIdx.x;
    const int w = t & 63;
    const int c0 = t >> 6;

    const float* tb = theta + b * 8;
    const float t0 = tb[0], t1 = tb[1], t2 = tb[2];
    const float t3 = tb[3], t4 = tb[4], t5 = tb[5];

    float w00, w10, w01, w11;
    int cy0, cy1, cx0, cx1;
    sample_one(h, w, t0, t1, t2, t3, t4, t5, w00, w10, w01, w11, cy0, cy1, cx0, cx1);

    const bool tailblk = (b == 255) && (h >= 32);
    const int r0 = cy0 * 64, r1 = cy1 * 64;

#pragma unroll
    for (int i = 0; i < 8; ++i) {
        const int c = c0 + 4 * i;
        const float* img = x + (((size_t)b * 32 + c) << 12);
        const float v = w00 * img[r0 + cx0] + w10 * img[r0 + cx1]
                      + w01 * img[r1 + cx0] + w11 * img[r1 + cx1];
        if (!(tailblk && c == 31)) {
            __builtin_nontemporal_store(v, &out[(((size_t)b * 32 + c) << 12) + h * 64 + w]);
        }
    }
}

// Last 2048 elements: b=255, c=31, h in [32,64). This region of d_out holds theta:
// read theta first, sync, then overwrite.
__global__ __launch_bounds__(256) void st_sample_tail(const float* __restrict__ x,
                                                      float* out,
                                                      long long tailstart) {
    const float* tb = out + tailstart + 255 * 8;
    const float t0 = tb[0], t1 = tb[1], t2 = tb[2];
    const float t3 = tb[3], t4 = tb[4], t5 = tb[5];

    const int t = threadIdx.x;
    float vals[8];
#pragma unroll
    for (int i = 0; i < 8; ++i) {
        const long long e = tailstart + (long long)i * 256 + t;
        const int w = (int)(e & 63);
        const int h = (int)((e >> 6) & 63);
        const int c = (int)((e >> 12) & 31);
        const int b = (int)(e >> 17);
        float w00, w10, w01, w11;
        int cy0, cy1, cx0, cx1;
        sample_one(h, w, t0, t1, t2, t3, t4, t5, w00, w10, w01, w11, cy0, cy1, cx0, cx1);
        const float* img = x + (((size_t)b * 32 + c) << 12);
        vals[i] = w00 * img[cy0 * 64 + cx0] + w10 * img[cy0 * 64 + cx1]
                + w01 * img[cy1 * 64 + cx0] + w11 * img[cy1 * 64 + cx1];
    }
    __syncthreads();
#pragma unroll
    for (int i = 0; i < 8; ++i) {
        const long long e = tailstart + (long long)i * 256 + t;
        out[e] = vals[i];
    }
}

extern "C" void kernel_launch(void* const* d_in, const int* in_sizes, int n_in,
                              void* d_out, int out_size, void* d_ws, size_t ws_size,
                              hipStream_t stream) {
    const float* x  = (const float*)d_in[0];
    const float* w1 = (const float*)d_in[1];
    const float* b1 = (const float*)d_in[2];
    const float* w2 = (const float*)d_in[3];
    const float* b2 = (const float*)d_in[4];
    const float* w3 = (const float*)d_in[5];
    const float* b3 = (const float*)d_in[6];
    float* out = (float*)d_out;

    const long long tailstart = (long long)out_size - 2048;
    float* partial = out;                   // [256][512][32] = 16.8 MB, overwritten by st_sample
    float* theta   = out + tailstart;       // [256][8] in the tail 2048

    st_lin1<<<1024, 256, 0, stream>>>(x, w1, partial);
    st_mlp<<<256, 256, 0, stream>>>(partial, b1, w2, b2, w3, b3, theta);
    st_sample<<<256 * 64, 256, 0, stream>>>(x, theta, out);
    st_sample_tail<<<1, 256, 0, stream>>>(x, out, tailstart);
}

// Round 6
// 102.864 us; speedup vs baseline: 3.0800x; 1.0104x over previous
//
#include <hip/hip_runtime.h>
#include <hip/hip_bf16.h>

// Spatial Transformer: B=256, C=32, H=W=64. All fp32 in/out.
//   k1: bf16 MFMA k-split GEMM x[256,131072] @ w1^T -> partial[256][1024][32] (d_out head)
//       w staged once/block into LDS as bf16 frags (conflict-free b128 reads);
//       x direct global->VGPR; KC=128, grid 2048 for ~6 waves/SIMD latency hiding
//   k2: reduce partials (contiguous stream) + bias/relu + layer2 + layer3 -> theta[256,8]
//   k3: affine grid + bilinear sample (all but last 2048 elems)
//   k3tail: last 2048 elems (overlap theta storage; read-then-write)

#define K_TOT 131072
#define KC    128           // k per block
#define KSPL  (K_TOT/KC)    // 1024 k-chunks; partial layout [b][kc][j]
#define NS    (KC/32)       // 4 MFMA steps per block

typedef short s16x8 __attribute__((ext_vector_type(8)));   // 8 bf16 in 4 VGPRs
typedef float f32x4 __attribute__((ext_vector_type(4)));

__device__ __forceinline__ short f2bf(float f) {
    return __builtin_bit_cast(short, __float2bfloat16(f));  // RNE scalar cast; compiler fuses to cvt_pk
}

__device__ __forceinline__ s16x8 cvt8(float4 a, float4 b) {
    s16x8 r;
    r[0] = f2bf(a.x); r[1] = f2bf(a.y); r[2] = f2bf(a.z); r[3] = f2bf(a.w);
    r[4] = f2bf(b.x); r[5] = f2bf(b.y); r[6] = f2bf(b.z); r[7] = f2bf(b.w);
    return r;
}

__global__ __launch_bounds__(256, 6) void st_lin1(const float* __restrict__ x,
                                                  const float* __restrict__ w1,
                                                  float* __restrict__ partial) {
    // XCD swizzle: contiguous kc range per XCD -> per-XCD w working set 2 MB (L2-resident).
    const int bid = blockIdx.x;             // 0..2047
    const int xcd = bid & 7;
    const int s8  = bid >> 3;               // 0..255
    const int kc  = xcd * 128 + (s8 >> 1);  // 0..1023
    const int bg  = s8 & 1;                 // 0..1

    const int t    = threadIdx.x;
    const int wv   = t >> 6;                // wave 0..3 -> 32-batch subtile
    const int lane = t & 63;
    const int m    = lane & 15;             // A: row within 16-tile; B: col (j)
    const int kb   = lane >> 4;             // k-block 0..3 (8 k each)

    // ---- stage w slice (32 rows x KC k) as bf16 MFMA B-frags in LDS ----
    // frag index f = (s*2+jh)*64 + kb*16 + m  ->  LDS addr f*16B (canonical: lane*16B contiguous)
    __shared__ s16x8 wlds[NS * 2 * 64];
#pragma unroll
    for (int rep = 0; rep < 2; ++rep) {
        const int f  = rep * 256 + t;
        const int fm = f & 15;
        const int fk = (f >> 4) & 3;
        const int fj = (f >> 6) & 1;
        const int fs = f >> 7;
        const float* wp = w1 + (size_t)(fj * 16 + fm) * K_TOT + (size_t)kc * KC + fs * 32 + fk * 8;
        const float4 wa = *(const float4*)(wp);
        const float4 wb = *(const float4*)(wp + 4);
        wlds[f] = cvt8(wa, wb);
    }
    __syncthreads();

    const int b0 = bg * 128 + wv * 32;
    const long long k0 = (long long)kc * KC + kb * 8;

    const float* xp0 = x + (size_t)(b0 + m)      * K_TOT + k0;
    const float* xp1 = x + (size_t)(b0 + 16 + m) * K_TOT + k0;

    f32x4 acc00 = {0.f,0.f,0.f,0.f}, acc01 = {0.f,0.f,0.f,0.f};
    f32x4 acc10 = {0.f,0.f,0.f,0.f}, acc11 = {0.f,0.f,0.f,0.f};

#pragma unroll
    for (int ss = 0; ss < NS; ++ss) {
        const int o = ss * 32;
        const float4 a00 = *(const float4*)(xp0 + o);
        const float4 a01 = *(const float4*)(xp0 + o + 4);
        const float4 a10 = *(const float4*)(xp1 + o);
        const float4 a11 = *(const float4*)(xp1 + o + 4);
        const s16x8 af0 = cvt8(a00, a01);
        const s16x8 af1 = cvt8(a10, a11);
        const s16x8 bf0 = wlds[(ss * 2 + 0) * 64 + lane];
        const s16x8 bf1 = wlds[(ss * 2 + 1) * 64 + lane];
        acc00 = __builtin_amdgcn_mfma_f32_16x16x32_bf16(af0, bf0, acc00, 0, 0, 0);
        acc01 = __builtin_amdgcn_mfma_f32_16x16x32_bf16(af0, bf1, acc01, 0, 0, 0);
        acc10 = __builtin_amdgcn_mfma_f32_16x16x32_bf16(af1, bf0, acc10, 0, 0, 0);
        acc11 = __builtin_amdgcn_mfma_f32_16x16x32_bf16(af1, bf1, acc11, 0, 0, 0);
    }

    // C/D layout: col(j) = lane&15, row(b within 16-tile) = kb*4 + reg.
    // partial[b][kc][j], strideB = KSPL*32 floats.
    const size_t strideB = (size_t)KSPL * 32;
    float* p0 = partial + (size_t)(b0 + kb * 4) * strideB + (size_t)kc * 32 + m;
#pragma unroll
    for (int rr = 0; rr < 4; ++rr) {
        p0[(size_t)rr * strideB]             = acc00[rr];   // b=b0+kb*4+rr,    j=m
        p0[(size_t)rr * strideB + 16]        = acc01[rr];   //                  j=16+m
        p0[(size_t)(16 + rr) * strideB]      = acc10[rr];   // b=b0+16+kb*4+rr, j=m
        p0[(size_t)(16 + rr) * strideB + 16] = acc11[rr];   //                  j=16+m
    }
}

__global__ __launch_bounds__(256) void st_mlp(const float* __restrict__ partial,
                                              const float* __restrict__ b1,
                                              const float* __restrict__ w2,
                                              const float* __restrict__ b2,
                                              const float* __restrict__ w3,
                                              const float* __restrict__ b3,
                                              float* __restrict__ theta) {
    const int b = blockIdx.x;
    const int t = threadIdx.x;
    const float* pb = partial + (size_t)b * KSPL * 32;   // 128 KB contiguous per block

    // Coalesced contiguous stream: thread t reads float4 at (i*256+t)*4.
    // Its j-quad class is constant: (i*1024 + 4t) mod 32 = (4t)&31.
    float4 v = {0.f, 0.f, 0.f, 0.f};
#pragma unroll
    for (int i = 0; i < KSPL * 32 / 1024; ++i) {
        const float4 u = *(const float4*)(pb + (size_t)(i * 256 + t) * 4);
        v.x += u.x; v.y += u.y; v.z += u.z; v.w += u.w;
    }

    __shared__ float4 ld[256];
    __shared__ float s1s[32];
    __shared__ float s2s[32];
    ld[t] = v;
    __syncthreads();
    // Tree-reduce with offsets that are multiples of 8 -> merges only same j-quad classes.
#pragma unroll
    for (int off = 128; off >= 8; off >>= 1) {
        if (t < off) {
            float4 a = ld[t];
            const float4 c = ld[t + off];
            a.x += c.x; a.y += c.y; a.z += c.z; a.w += c.w;
            ld[t] = a;
        }
        __syncthreads();
    }
    if (t < 8) {   // thread t holds j-quad 4t..4t+3
        const float4 q = ld[t];
        s1s[4 * t + 0] = fmaxf(q.x + b1[4 * t + 0], 0.f);
        s1s[4 * t + 1] = fmaxf(q.y + b1[4 * t + 1], 0.f);
        s1s[4 * t + 2] = fmaxf(q.z + b1[4 * t + 2], 0.f);
        s1s[4 * t + 3] = fmaxf(q.w + b1[4 * t + 3], 0.f);
    }
    __syncthreads();
    if (t < 32) {
        float vv = b2[t];
#pragma unroll
        for (int i = 0; i < 32; ++i) vv += w2[t * 32 + i] * s1s[i];
        s2s[t] = fmaxf(vv, 0.f);
    }
    __syncthreads();
    if (t < 8) {
        float vv = 0.f;
        if (t < 6) {
            vv = b3[t];
#pragma unroll
            for (int i = 0; i < 32; ++i) vv += w3[t * 32 + i] * s2s[i];
        }
        theta[b * 8 + t] = vv;
    }
}

__device__ __forceinline__ void sample_one(int h, int w,
                                           float t0, float t1, float t2,
                                           float t3, float t4, float t5,
                                           float& wgt00, float& wgt10, float& wgt01, float& wgt11,
                                           int& cy0, int& cy1, int& cx0, int& cx1) {
    const float xs = ((float)w - 31.5f) * 0.03125f;
    const float ys = ((float)h - 31.5f) * 0.03125f;
    const float gxn = fmaf(t1, ys, fmaf(t0, xs, t2));
    const float gyn = fmaf(t4, ys, fmaf(t3, xs, t5));
    const float gx = fmaf(gxn, 32.f, 31.5f);
    const float gy = fmaf(gyn, 32.f, 31.5f);
    const float x0f = floorf(gx), y0f = floorf(gy);
    const float wx1 = gx - x0f, wx0 = 1.f - wx1;
    const float wy1 = gy - y0f, wy0 = 1.f - wy1;
    const int ix = (int)x0f, iy = (int)y0f;
    const bool vx0 = (ix >= 0) && (ix < 64);
    const bool vx1 = (ix >= -1) && (ix < 63);
    const bool vy0 = (iy >= 0) && (iy < 64);
    const bool vy1 = (iy >= -1) && (iy < 63);
    cx0 = min(max(ix, 0), 63);
    cx1 = min(max(ix + 1, 0), 63);
    cy0 = min(max(iy, 0), 63);
    cy1 = min(max(iy + 1, 0), 63);
    wgt00 = wx0 * wy0 * ((vx0 && vy0) ? 1.f : 0.f);
    wgt10 = wx1 * wy0 * ((vx1 && vy0) ? 1.f : 0.f);
    wgt01 = wx0 * wy1 * ((vx0 && vy1) ? 1.f : 0.f);
    wgt11 = wx1 * wy1 * ((vx1 && vy1) ? 1.f : 0.f);
}

__global__ __launch_bounds__(256) void st_sample(const float* __restrict__ x,
                                                 const float* theta,
                                                 float* out) {
    const int bid = blockIdx.x;
    const int b = bid >> 6;
    const int h = bid & 63;
    const int t = threadIdx.x;
    const int w = t & 63;
    const int c0 = t >> 6;

    const float* tb = theta + b * 8;
    const float t0 = tb[0], t1 = tb[1], t2 = tb[2];
    const float t3 = tb[3], t4 = tb[4], t5 = tb[5];

    float w00, w10, w01, w11;
    int cy0, cy1, cx0, cx1;
    sample_one(h, w, t0, t1, t2, t3, t4, t5, w00, w10, w01, w11, cy0, cy1, cx0, cx1);

    const bool tailblk = (b == 255) && (h >= 32);
    const int r0 = cy0 * 64, r1 = cy1 * 64;

#pragma unroll
    for (int i = 0; i < 8; ++i) {
        const int c = c0 + 4 * i;
        const float* img = x + (((size_t)b * 32 + c) << 12);
        const float v = w00 * img[r0 + cx0] + w10 * img[r0 + cx1]
                      + w01 * img[r1 + cx0] + w11 * img[r1 + cx1];
        if (!(tailblk && c == 31)) {
            __builtin_nontemporal_store(v, &out[(((size_t)b * 32 + c) << 12) + h * 64 + w]);
        }
    }
}

// Last 2048 elements: b=255, c=31, h in [32,64). This region of d_out holds theta:
// read theta first, sync, then overwrite.
__global__ __launch_bounds__(256) void st_sample_tail(const float* __restrict__ x,
                                                      float* out,
                                                      long long tailstart) {
    const float* tb = out + tailstart + 255 * 8;
    const float t0 = tb[0], t1 = tb[1], t2 = tb[2];
    const float t3 = tb[3], t4 = tb[4], t5 = tb[5];

    const int t = threadIdx.x;
    float vals[8];
#pragma unroll
    for (int i = 0; i < 8; ++i) {
        const long long e = tailstart + (long long)i * 256 + t;
        const int w = (int)(e & 63);
        const int h = (int)((e >> 6) & 63);
        const int c = (int)((e >> 12) & 31);
        const int b = (int)(e >> 17);
        float w00, w10, w01, w11;
        int cy0, cy1, cx0, cx1;
        sample_one(h, w, t0, t1, t2, t3, t4, t5, w00, w10, w01, w11, cy0, cy1, cx0, cx1);
        const float* img = x + (((size_t)b * 32 + c) << 12);
        vals[i] = w00 * img[cy0 * 64 + cx0] + w10 * img[cy0 * 64 + cx1]
                + w01 * img[cy1 * 64 + cx0] + w11 * img[cy1 * 64 + cx1];
    }
    __syncthreads();
#pragma unroll
    for (int i = 0; i < 8; ++i) {
        const long long e = tailstart + (long long)i * 256 + t;
        out[e] = vals[i];
    }
}

extern "C" void kernel_launch(void* const* d_in, const int* in_sizes, int n_in,
                              void* d_out, int out_size, void* d_ws, size_t ws_size,
                              hipStream_t stream) {
    const float* x  = (const float*)d_in[0];
    const float* w1 = (const float*)d_in[1];
    const float* b1 = (const float*)d_in[2];
    const float* w2 = (const float*)d_in[3];
    const float* b2 = (const float*)d_in[4];
    const float* w3 = (const float*)d_in[5];
    const float* b3 = (const float*)d_in[6];
    float* out = (float*)d_out;

    const long long tailstart = (long long)out_size - 2048;
    float* partial = out;                   // [256][1024][32] = 33.5 MB, overwritten by st_sample
    float* theta   = out + tailstart;       // [256][8] in the tail 2048

    st_lin1<<<2048, 256, 0, stream>>>(x, w1, partial);
    st_mlp<<<256, 256, 0, stream>>>(partial, b1, w2, b2, w3, b3, theta);
    st_sample<<<256 * 64, 256, 0, stream>>>(x, theta, out);
    st_sample_tail<<<1, 256, 0, stream>>>(x, out, tailstart);
}